// Round 3
// baseline (119.250 us; speedup 1.0000x reference)
//
#include <hip/hip_runtime.h>
#include <hip/hip_bf16.h>

typedef __attribute__((ext_vector_type(8))) short bf16x8;
typedef __attribute__((ext_vector_type(4))) float f32x4;

#define N_PTS  500000
#define DIM    64
#define NCLUST 128
#define TILES  (N_PTS / 16)   // 31250, exact
#define NBLK   1024           // 4 blocks/CU resident at <=128 VGPR
#define LOG2E  1.44269504088896f
#define LN2    0.69314718055994f

static __device__ __forceinline__ unsigned short f2bf(float x) {
    union { float f; unsigned u; } un; un.f = x;
    unsigned u = un.u;
    u += 0x7fffu + ((u >> 16) & 1u);   // RNE
    return (unsigned short)(u >> 16);
}

static __device__ __forceinline__ float sq4(float4 v) {
    return v.x*v.x + v.y*v.y + v.z*v.z + v.w*v.w;
}

static __device__ __forceinline__ bf16x8 pack8(float4 a, float4 b) {
    union { bf16x8 v; __hip_bfloat162 h[4]; } u;
    u.h[0] = __float22bfloat162_rn(make_float2(a.x, a.y));
    u.h[1] = __float22bfloat162_rn(make_float2(a.z, a.w));
    u.h[2] = __float22bfloat162_rn(make_float2(b.x, b.y));
    u.h[3] = __float22bfloat162_rn(make_float2(b.z, b.w));
    return u.v;
}

__global__ __launch_bounds__(256, 4) void kmeans_lse_kernel(
    const float* __restrict__ X, const float* __restrict__ centers,
    const float* __restrict__ vars_, const float* __restrict__ prs,
    const float* __restrict__ threshold, float* __restrict__ out)
{
    // Scaled centers c'_j = c_j/var_j*log2e as bf16, XOR-slot-swizzled:
    //   element (j,k) at ushort index j*64 + (((k>>3) ^ (j&7))<<3) + (k&7)
    __shared__ unsigned short sC[NCLUST * DIM];   // 16 KB
    // Per-cluster constants, quad-interleaved: chunk c=j>>2:
    //   sAB[c*8 + (j&3)] = a_j = -0.5/var_j*log2e
    //   sAB[c*8 + 4 + (j&3)] = b_j = a_j*||c_j||^2 + log2(prs_j)
    __shared__ float sAB[NCLUST * 2];             // 1 KB

    const int tid = threadIdx.x;
    {   // init: 2 threads per cluster row (halves), 256 threads total
        const int j = tid >> 1, h = tid & 1;
        const float inv = 1.0f / vars_[j];
        const float cscale = inv * LOG2E;
        float c2p = 0.0f;
        #pragma unroll
        for (int k = 32*h; k < 32*h + 32; k += 4) {
            float4 c = *(const float4*)(centers + j*DIM + k);
            c2p = fmaf(c.x, c.x, fmaf(c.y, c.y, fmaf(c.z, c.z, fmaf(c.w, c.w, c2p))));
            const int base = j*64 + (((k >> 3) ^ (j & 7)) << 3) + (k & 7);
            sC[base+0] = f2bf(c.x * cscale);
            sC[base+1] = f2bf(c.y * cscale);
            sC[base+2] = f2bf(c.z * cscale);
            sC[base+3] = f2bf(c.w * cscale);
        }
        c2p += __shfl_xor(c2p, 1);   // partner half of same row
        if (h == 0) {
            const float a = -0.5f * inv * LOG2E;
            sAB[(j>>2)*8 + (j&3)]     = a;
            sAB[(j>>2)*8 + 4 + (j&3)] = fmaf(a, c2p, __log2f(prs[j]));
        }
    }
    __syncthreads();

    const int lane = tid & 63;
    const int wid  = tid >> 6;
    const int g    = lane >> 4;   // k-chunk group (0..3)
    const int r    = lane & 15;   // point-in-tile (B col) / cluster-row (A row)

    // lane-invariant LDS offsets
    const unsigned co1 = (unsigned)r*64 + ((unsigned)(g ^ (r & 7)) << 3);  // chunk g
    const unsigned co2 = co1 ^ 32;                                         // chunk 4+g
    const unsigned abo = (unsigned)g * 8;

    const float thr = threshold[0];
    const int S = NBLK * 4;        // grid stride in tiles (4096)
    int tile = blockIdx.x*4 + wid;
    const size_t lane_off = (size_t)r * DIM + 8*g;

    const float* pc = X + (size_t)tile*16*DIM + lane_off;
    float4 c0 = *(const float4*)(pc),    c1 = *(const float4*)(pc+4),
           c2v= *(const float4*)(pc+32), c3 = *(const float4*)(pc+36);
    float4 n0{}, n1{}, n2{}, n3{};
    int nt = tile + S;

    for (;;) {
        if (nt < TILES) {          // depth-1 prefetch (wave-uniform branch)
            const float* pn = X + (size_t)nt*16*DIM + lane_off;
            n0 = *(const float4*)(pn);    n1 = *(const float4*)(pn+4);
            n2 = *(const float4*)(pn+32); n3 = *(const float4*)(pn+36);
        }

        // full ||x_r||^2 into every lane (2 shuffles)
        float ss = sq4(c0) + sq4(c1) + sq4(c2v) + sq4(c3);
        ss += __shfl_xor(ss, 16);
        ss += __shfl_xor(ss, 32);

        bf16x8 B0 = pack8(c0, c1);    // points = B operand, k-chunk g / 4+g
        bf16x8 B1 = pack8(c2v, c3);

        // acc[t][q] = logit~ of cluster 16t+4g+q for point r (log2 domain)
        f32x4 acc[8];
        #pragma unroll
        for (int t = 0; t < 8; ++t) {
            f32x4 a4 = *(const f32x4*)&sAB[t*32 + abo];
            f32x4 b4 = *(const f32x4*)&sAB[t*32 + abo + 4];
            #pragma unroll
            for (int q = 0; q < 4; ++q) acc[t][q] = fmaf(a4[q], ss, b4[q]);
            bf16x8 C0 = *(const bf16x8*)&sC[t*1024 + co1];
            bf16x8 C1 = *(const bf16x8*)&sC[t*1024 + co2];
            acc[t] = __builtin_amdgcn_mfma_f32_16x16x32_bf16(C0, B0, acc[t], 0, 0, 0);
            acc[t] = __builtin_amdgcn_mfma_f32_16x16x32_bf16(C1, B1, acc[t], 0, 0, 0);
        }

        // lane-local max over 32, then combine the 4 g-lanes of this point
        float mx = acc[0][0];
        #pragma unroll
        for (int t = 0; t < 8; ++t)
            #pragma unroll
            for (int q = 0; q < 4; ++q) mx = fmaxf(mx, acc[t][q]);
        mx = fmaxf(mx, __shfl_xor(mx, 16));
        mx = fmaxf(mx, __shfl_xor(mx, 32));

        float sm = 0.0f;
        #pragma unroll
        for (int t = 0; t < 8; ++t)
            #pragma unroll
            for (int q = 0; q < 4; ++q)
                sm += __builtin_amdgcn_exp2f(acc[t][q] - mx);
        sm += __shfl_xor(sm, 16);
        sm += __shfl_xor(sm, 32);

        if (lane < 16) {
            out[tile*16 + lane] =
                fmaf(mx + __builtin_amdgcn_logf(sm), LN2, -thr);  // v_log_f32 = log2
        }

        if (nt >= TILES) break;
        tile = nt; nt += S;
        c0 = n0; c1 = n1; c2v = n2; c3 = n3;
    }
}

extern "C" void kernel_launch(void* const* d_in, const int* in_sizes, int n_in,
                              void* d_out, int out_size, void* d_ws, size_t ws_size,
                              hipStream_t stream) {
    const float* X         = (const float*)d_in[0];
    const float* centers   = (const float*)d_in[1];
    const float* vars_     = (const float*)d_in[2];
    const float* prs       = (const float*)d_in[3];
    const float* threshold = (const float*)d_in[4];
    float* out = (float*)d_out;
    (void)in_sizes; (void)n_in; (void)out_size; (void)d_ws; (void)ws_size;

    kmeans_lse_kernel<<<NBLK, 256, 0, stream>>>(X, centers, vars_, prs, threshold, out);
}

// Round 4
// 34.357 us; speedup vs baseline: 3.4709x; 3.4709x over previous
//
#include <hip/hip_runtime.h>
#include <hip/hip_bf16.h>

typedef __attribute__((ext_vector_type(8))) short bf16x8;
typedef __attribute__((ext_vector_type(4))) float f32x4;
typedef __attribute__((ext_vector_type(8))) _Float16 h8;
typedef __attribute__((ext_vector_type(2))) _Float16 h2;

#define N_PTS  500000
#define DIM    64
#define NCLUST 128
#define TILES  (N_PTS / 16)   // 31250, exact
#define NBLK   768            // 3 blocks/CU resident at <=170 VGPR
#define LOG2E  1.44269504088896f
#define LN2    0.69314718055994f

static __device__ __forceinline__ unsigned short f2bf(float x) {
    union { float f; unsigned u; } un; un.f = x;
    unsigned u = un.u;
    u += 0x7fffu + ((u >> 16) & 1u);   // RNE
    return (unsigned short)(u >> 16);
}

static __device__ __forceinline__ float sq4(float4 v) {
    return v.x*v.x + v.y*v.y + v.z*v.z + v.w*v.w;
}

static __device__ __forceinline__ bf16x8 pack8(float4 a, float4 b) {
    union { bf16x8 v; __hip_bfloat162 h[4]; } u;
    u.h[0] = __float22bfloat162_rn(make_float2(a.x, a.y));
    u.h[1] = __float22bfloat162_rn(make_float2(a.z, a.w));
    u.h[2] = __float22bfloat162_rn(make_float2(b.x, b.y));
    u.h[3] = __float22bfloat162_rn(make_float2(b.z, b.w));
    return u.v;
}

__global__ __launch_bounds__(256, 3) void kmeans_lse_kernel(
    const float* __restrict__ X, const float* __restrict__ centers,
    const float* __restrict__ vars_, const float* __restrict__ prs,
    const float* __restrict__ threshold, float* __restrict__ out)
{
    // Scaled centers c'_j = c_j/var_j*log2e as bf16, XOR-slot-swizzled:
    //   element (j,k) at ushort index j*64 + (((k>>3) ^ (j&7))<<3) + (k&7)
    __shared__ unsigned short sC[NCLUST * DIM];       // 16 KB (used pre-loop only)
    // Per-cluster LSE constants as f16, 16B block per (t,g) quad:
    //   block (j>>2): halfs [a(4j..4j+3) | b(4j..4j+3)]
    //   a_j = -0.5/var_j*log2e,  b_j = a_j*||c_j||^2 + log2(prs_j)
    __shared__ __align__(16) _Float16 sABh[NCLUST * 2];  // 512 B

    const int tid = threadIdx.x;
    {   // init: 2 threads per cluster row (halves)
        const int j = tid >> 1, h = tid & 1;
        const float inv = 1.0f / vars_[j];
        const float cscale = inv * LOG2E;
        float c2p = 0.0f;
        #pragma unroll
        for (int k = 32*h; k < 32*h + 32; k += 4) {
            float4 c = *(const float4*)(centers + j*DIM + k);
            c2p = fmaf(c.x, c.x, fmaf(c.y, c.y, fmaf(c.z, c.z, fmaf(c.w, c.w, c2p))));
            const int base = j*64 + (((k >> 3) ^ (j & 7)) << 3) + (k & 7);
            sC[base+0] = f2bf(c.x * cscale);
            sC[base+1] = f2bf(c.y * cscale);
            sC[base+2] = f2bf(c.z * cscale);
            sC[base+3] = f2bf(c.w * cscale);
        }
        c2p += __shfl_xor(c2p, 1);   // partner half of same row
        if (h == 0) {
            const float a = -0.5f * inv * LOG2E;
            const float b = fmaf(a, c2p, __log2f(prs[j]));
            sABh[(j>>2)*8 + (j&3)]     = (_Float16)a;
            sABh[(j>>2)*8 + 4 + (j&3)] = (_Float16)b;
        }
    }
    __syncthreads();

    const int lane = tid & 63;
    const int wid  = tid >> 6;
    const int g    = lane >> 4;   // k-chunk group (0..3)
    const int r    = lane & 15;   // point-in-tile (B col) / cluster-row (A row)

    // Center fragments -> registers for the whole loop (64 VGPRs).
    const unsigned co1 = (unsigned)r*64 + ((unsigned)(g ^ (r & 7)) << 3);  // chunk g
    const unsigned co2 = co1 ^ 32;                                         // chunk 4+g
    bf16x8 Cf0[8], Cf1[8];
    #pragma unroll
    for (int t = 0; t < 8; ++t) {
        Cf0[t] = *(const bf16x8*)&sC[t*1024 + co1];
        Cf1[t] = *(const bf16x8*)&sC[t*1024 + co2];
    }

    const float thr = threshold[0];
    const int S = NBLK * 4;        // grid stride in tiles (3072)
    int tile = blockIdx.x*4 + wid;
    const size_t lane_off = (size_t)r * DIM + 8*g;

    const float* pc = X + (size_t)tile*16*DIM + lane_off;
    float4 c0 = *(const float4*)(pc),    c1 = *(const float4*)(pc+4),
           c2v= *(const float4*)(pc+32), c3 = *(const float4*)(pc+36);
    float4 n0{}, n1{}, n2{}, n3{};
    int nt = tile + S;

    for (;;) {
        if (nt < TILES) {          // depth-1 prefetch (wave-uniform branch)
            const float* pn = X + (size_t)nt*16*DIM + lane_off;
            n0 = *(const float4*)(pn);    n1 = *(const float4*)(pn+4);
            n2 = *(const float4*)(pn+32); n3 = *(const float4*)(pn+36);
        }

        // full ||x_r||^2 into every lane (2 shuffles)
        float ss = sq4(c0) + sq4(c1) + sq4(c2v) + sq4(c3);
        ss += __shfl_xor(ss, 16);
        ss += __shfl_xor(ss, 32);

        bf16x8 B0 = pack8(c0, c1);    // points = B operand, k-chunks g / 4+g
        bf16x8 B1 = pack8(c2v, c3);

        const h2 ss2 = {(_Float16)ss, (_Float16)ss};

        // acc[t][q] = logit~ of cluster 16t+4g+q for point r (log2 domain)
        f32x4 acc[8];
        #pragma unroll
        for (int t = 0; t < 8; ++t) {
            // one broadcast b128: [a-quad | b-quad] as f16 (volatile: keep in LDS)
            h8 ab = *(const volatile h8*)&sABh[t*32 + g*8];
            h2 i01 = __builtin_shufflevector(ab, ab, 0, 1) * ss2
                   + __builtin_shufflevector(ab, ab, 4, 5);
            h2 i23 = __builtin_shufflevector(ab, ab, 2, 3) * ss2
                   + __builtin_shufflevector(ab, ab, 6, 7);
            acc[t][0] = (float)i01[0]; acc[t][1] = (float)i01[1];
            acc[t][2] = (float)i23[0]; acc[t][3] = (float)i23[1];
            acc[t] = __builtin_amdgcn_mfma_f32_16x16x32_bf16(Cf0[t], B0, acc[t], 0, 0, 0);
            acc[t] = __builtin_amdgcn_mfma_f32_16x16x32_bf16(Cf1[t], B1, acc[t], 0, 0, 0);
        }

        // lane-local max over 32 clusters, then combine the 4 g-lanes
        float mx = acc[0][0];
        #pragma unroll
        for (int t = 0; t < 8; ++t)
            #pragma unroll
            for (int q = 0; q < 4; ++q) mx = fmaxf(mx, acc[t][q]);
        mx = fmaxf(mx, __shfl_xor(mx, 16));
        mx = fmaxf(mx, __shfl_xor(mx, 32));

        // sum of exp2 with 4 independent partials (shorter dep chains)
        float s0 = 0.f, s1 = 0.f, s2 = 0.f, s3 = 0.f;
        #pragma unroll
        for (int t = 0; t < 8; ++t) {
            s0 += __builtin_amdgcn_exp2f(acc[t][0] - mx);
            s1 += __builtin_amdgcn_exp2f(acc[t][1] - mx);
            s2 += __builtin_amdgcn_exp2f(acc[t][2] - mx);
            s3 += __builtin_amdgcn_exp2f(acc[t][3] - mx);
        }
        float sm = (s0 + s1) + (s2 + s3);
        sm += __shfl_xor(sm, 16);
        sm += __shfl_xor(sm, 32);

        if (lane < 16) {
            out[tile*16 + lane] =
                fmaf(mx + __builtin_amdgcn_logf(sm), LN2, -thr);  // v_log_f32 = log2
        }

        if (nt >= TILES) break;
        tile = nt; nt += S;
        c0 = n0; c1 = n1; c2v = n2; c3 = n3;
    }
}

extern "C" void kernel_launch(void* const* d_in, const int* in_sizes, int n_in,
                              void* d_out, int out_size, void* d_ws, size_t ws_size,
                              hipStream_t stream) {
    const float* X         = (const float*)d_in[0];
    const float* centers   = (const float*)d_in[1];
    const float* vars_     = (const float*)d_in[2];
    const float* prs       = (const float*)d_in[3];
    const float* threshold = (const float*)d_in[4];
    float* out = (float*)d_out;
    (void)in_sizes; (void)n_in; (void)out_size; (void)d_ws; (void)ws_size;

    kmeans_lse_kernel<<<NBLK, 256, 0, stream>>>(X, centers, vars_, prs, threshold, out);
}